// Round 5
// baseline (751.565 us; speedup 1.0000x reference)
//
#include <hip/hip_runtime.h>
#include <cstdint>
#include <cstddef>

#define NSAMP 4096
#define KDIM  512
#define TOT   49536   // 3 * (128*128 + 128)
#define NUMN  387     // TOT / 128
#define LCHUNK 16512  // 128 + 128*128, per-layer temp stride

typedef __attribute__((ext_vector_type(8))) __bf16 bf16x8;
typedef __attribute__((ext_vector_type(4))) __bf16 bf16x4;
typedef __attribute__((ext_vector_type(4))) float  f32x4;

#define AS1 __attribute__((address_space(1)))
#define AS3 __attribute__((address_space(3)))

// ---------------------------------------------------------------------------
// fp32 -> bf16 cast, 4 elements per thread (float4 read, 8B write)
// ---------------------------------------------------------------------------
__global__ void cast_bf16(const float* __restrict__ in, __bf16* __restrict__ out, int n4) {
    int i = blockIdx.x * blockDim.x + threadIdx.x;
    int stride = gridDim.x * blockDim.x;
    for (; i < n4; i += stride) {
        float4 v = ((const float4*)in)[i];
        bf16x4 o = { (__bf16)v.x, (__bf16)v.y, (__bf16)v.z, (__bf16)v.w };
        ((bf16x4*)out)[i] = o;
    }
}

// ---------------------------------------------------------------------------
// Hypernetwork GEMM: C[m][n] = sum_k A[m][k]*B[n][k] + bias[n]
// R10: BARRIER-FREE K-LOOP. R1/R4 both sat at ~611 TF = the documented
// 128^2+2phase structural ceiling (m228d 622 TF): every K-step moved 64KB
// global->LDS + 32KB LDS->reg per CU, drained vmcnt(0)+lgkmcnt(0) at 8
// barriers per block for only 8 K-steps. K=512 is short enough that the
// WHOLE 128-row A-panel (128x512 bf16 = 128KB) fits in LDS (128KB static
// LDS proven working in R2's counters). B fragments are 16B/lane contiguous
// in k -> loaded straight from global into VGPRs (16 cachelines/wave-instr,
// perfectly coalesced; same-XCD L2 panels hot via the proven swizzle), no
// LDS, no inter-wave sharing. K-loop = {prefetch B(kt+1) -> ds_read A-frags
// -> 32 MFMA}, ZERO barriers, compiler free to pipeline with counted
// per-register waits. 1 block/CU (by LDS), 1 wave/SIMD: ILP carries
// latency; ~160 VGPR of 512 available. Frag + epilogue formulas verbatim
// from the proven kernel (2Mx2N wave split unchanged).
// ---------------------------------------------------------------------------
__global__ __launch_bounds__(256, 1) void hyper_gemm(
    const __bf16* __restrict__ A, const __bf16* __restrict__ B,
    const float* __restrict__ bias, __bf16* __restrict__ C)
{
    __shared__ __bf16 As[128 * KDIM];   // 128 KB: full-K A panel

    const int tid   = threadIdx.x;
    const int lane  = tid & 63;
    const int quad  = lane >> 4;      // 0..3
    const int r16   = lane & 15;      // 0..15
    const int wv    = tid >> 6;       // 0..3
    const int waveM = wv >> 1;        // 0..1
    const int waveN = wv & 1;         // 0..1

    // ---- XCD-congruent swizzle: hw id -> (m_t, n_t)  (unchanged, proven)
    const int num_m = gridDim.y;                    // chunk/128
    const int id    = blockIdx.y * NUMN + blockIdx.x;
    const int gsz   = 8 * num_m;                    // supergroup block count
    const int s     = id / gsz;
    const int r     = id % gsz;
    const int base  = s * 8;
    int w = NUMN - base; if (w > 8) w = 8;          // partial last group (387%8=3)
    const int n_t = base + r % w;
    const int m_t = r / w;

    const int m0 = m_t * 128;   // chunk-local row
    const int n0 = n_t * 128;

    f32x4 acc[4][4] = {};

    // ---- stage full A panel: 32 passes x 4KB. Pass p: idx = p*256+tid ->
    // row = p*4 + wv, granule-in-row = lane (64 x 16B granules per 1KB row).
    // xor-swizzle per 64-elem k-block: src granule-in-block = (lane&7)^(row&7)
    // with row&7 = (4*(p&1)+wv)&7 -> two hoisted bases (p even/odd).
    {
        const __bf16* aE = A + (size_t)(m0 + wv) * KDIM
                         + (lane >> 3) * 64 + ((lane & 7) ^ wv) * 8;
        const __bf16* aO = A + (size_t)(m0 + wv) * KDIM
                         + (lane >> 3) * 64 + (((lane & 7) ^ wv) ^ 4) * 8;
#pragma unroll
        for (int p = 0; p < 32; ++p) {
            const __bf16* src = ((p & 1) ? aO : aE) + (size_t)p * 4 * KDIM;
            __builtin_amdgcn_global_load_lds((AS1 void*)src,
                (AS3 void*)(As + ((p * 256 + tid) * 8)), 16, 0, 0);
        }
    }

    // ---- B fragment base: lane reads row n0+waveN*64+j*16+r16, k-chunk
    // (kk*4+quad)*8 within tile kt. 4 lanes of a quad-column cover one 64B
    // line per row -> 16 lines per wave-instr, fully coalesced.
    const __bf16* gB = B + (size_t)(n0 + waveN * 64 + r16) * KDIM + quad * 8;

    bf16x8 bb[2][4][2];   // [kt parity][j][kk] — static after full unroll
#define LOADB(par, kt) { _Pragma("unroll") for (int j = 0; j < 4; ++j) { \
    _Pragma("unroll") for (int kk = 0; kk < 2; ++kk) { \
        bb[par][j][kk] = *(const bf16x8*)(gB + (size_t)j * 16 * KDIM + (kt) * 64 + kk * 32); } } }

    const int rsw = r16 & 7;          // read-phase swizzle key

    LOADB(0, 0);
    __syncthreads();   // single barrier: A panel staged (implicit vmcnt(0))

#pragma unroll
    for (int kt = 0; kt < 8; ++kt) {
        const int cur = kt & 1;
        if (kt < 7) LOADB(cur ^ 1, kt + 1);    // prefetch next B tile

        bf16x8 af[4][2];
#pragma unroll
        for (int i = 0; i < 4; ++i) {
            int rr = waveM * 64 + i * 16 + r16;
#pragma unroll
            for (int kk = 0; kk < 2; ++kk)
                af[i][kk] = *(const bf16x8*)(As + rr * KDIM + kt * 64
                                             + (((kk * 4 + quad) ^ rsw) * 8));
        }
#pragma unroll
        for (int i = 0; i < 4; ++i)
#pragma unroll
            for (int j = 0; j < 4; ++j) {
                acc[i][j] = __builtin_amdgcn_mfma_f32_16x16x32_bf16(
                    af[i][0], bb[cur][j][0], acc[i][j], 0, 0, 0);
                acc[i][j] = __builtin_amdgcn_mfma_f32_16x16x32_bf16(
                    af[i][1], bb[cur][j][1], acc[i][j], 0, 0, 0);
            }
    }
#undef LOADB

    // --- epilogue: C/D layout col=lane&15, row=(lane>>4)*4+reg. Fuse bias,
    // cast bf16, plain stores. Verbatim from the proven kernel.
#pragma unroll
    for (int j = 0; j < 4; ++j) {
        int n = n0 + waveN * 64 + j * 16 + r16;
        float bb2 = bias[n];
#pragma unroll
        for (int i = 0; i < 4; ++i) {
            int mbase = m0 + waveM * 64 + i * 16 + quad * 4;
#pragma unroll
            for (int rr = 0; rr < 4; ++rr) {
                C[(size_t)(mbase + rr) * TOT + n] = (__bf16)(acc[i][j][rr] + bb2);
            }
        }
    }
}

// ---------------------------------------------------------------------------
// Stage 2: per-sample 3-layer MLP with hypernetwork weights from temp chunk.
// Unchanged (T14 cross-layer weight prefetch; bias hoisted).
// ---------------------------------------------------------------------------
__global__ __launch_bounds__(256) void mlp_kernel(
    const float* __restrict__ x, const __bf16* __restrict__ temp,
    float* __restrict__ out, int samp0)
{
    const int n   = samp0 + blockIdx.x;   // global sample index
    const int tid = threadIdx.x;
    const int wv  = tid >> 6;             // 0..3
    const int l   = tid & 63;
    const int pg  = l >> 4;               // 0..3
    const int qg  = l & 15;               // 0..15

    __shared__ float h[128];
    __shared__ float partial[4][128];

    if (tid < 64) ((float2*)h)[tid] = ((const float2*)(x + (size_t)n * 128))[tid];

    const __bf16* row = temp + (size_t)blockIdx.x * TOT;   // chunk-local temp row

    // prefetch layer-0 weights (independent of h)
    bf16x8 w[8];
#pragma unroll
    for (int i = 0; i < 8; ++i)
        w[i] = *(const bf16x8*)(row + 128 + (size_t)(wv * 32 + i * 4 + pg) * 128 + qg * 8);

    int cum = 0;
#pragma unroll
    for (int layer = 0; layer < 3; ++layer) {
        bf16x8 wn[8];
        if (layer < 2) {
#pragma unroll
            for (int i = 0; i < 8; ++i)
                wn[i] = *(const bf16x8*)(row + cum + LCHUNK + 128
                        + (size_t)(wv * 32 + i * 4 + pg) * 128 + qg * 8);
        }
        float bv = 0.f;
        if (tid < 128) bv = (float)row[cum + tid];

        float acc[8] = {0, 0, 0, 0, 0, 0, 0, 0};
        __syncthreads();   // h ready
#pragma unroll
        for (int i = 0; i < 8; ++i) {
            float hp = h[wv * 32 + i * 4 + pg];
#pragma unroll
            for (int j = 0; j < 8; ++j) acc[j] += (float)w[i][j] * hp;
        }
#pragma unroll
        for (int j = 0; j < 8; ++j) {
            acc[j] += __shfl_xor(acc[j], 16);
            acc[j] += __shfl_xor(acc[j], 32);
        }
        if (pg == 0) {
#pragma unroll
            for (int j = 0; j < 8; ++j) partial[wv][qg * 8 + j] = acc[j];
        }
        __syncthreads();   // partials ready; everyone done reading h
        if (tid < 128) {
            float v = partial[0][tid] + partial[1][tid] + partial[2][tid] + partial[3][tid]
                    + bv;
            if (layer < 2) v = fmaxf(v, 0.f);
            h[tid] = v;
        }
        if (layer < 2) {
#pragma unroll
            for (int i = 0; i < 8; ++i) w[i] = wn[i];
        }
        cum += LCHUNK;
    }
    __syncthreads();
    if (tid < 64) ((float2*)(out + (size_t)n * 128))[tid] = ((const float2*)h)[tid];
}

// ---------------------------------------------------------------------------
extern "C" void kernel_launch(void* const* d_in, const int* in_sizes, int n_in,
                              void* d_out, int out_size, void* d_ws, size_t ws_size,
                              hipStream_t stream) {
    const float* int_x = (const float*)d_in[0];  // 4096 x 512
    const float* x     = (const float*)d_in[1];  // 4096 x 128
    const float* W     = (const float*)d_in[2];  // 49536 x 512
    const float* b     = (const float*)d_in[3];  // 49536
    float* out = (float*)d_out;                  // 4096 x 128

    // workspace layout (bf16): A_bf (4 MB) | W_bf (50.7 MB) | temp chunk
    char* ws = (char*)d_ws;
    __bf16* A_bf = (__bf16*)ws;
    size_t offA = (size_t)NSAMP * KDIM * 2;
    __bf16* W_bf = (__bf16*)(ws + offA);
    size_t offW = offA + (size_t)TOT * KDIM * 2;
    __bf16* temp = (__bf16*)(ws + offW);

    // Adaptive chunk: largest of {4096..128} whose temp fits remaining ws.
    // Deterministic given ws_size -> identical work every call (capture-safe).
    size_t remain = (ws_size > offW) ? (ws_size - offW) : 0;
    int chunk = 128;
    for (int c = 4096; c >= 128; c >>= 1) {
        if ((size_t)c * TOT * 2 <= remain) { chunk = c; break; }
    }

    int nA4 = NSAMP * KDIM / 4;
    cast_bf16<<<(nA4 + 255) / 256, 256, 0, stream>>>(int_x, A_bf, nA4);
    int nW4 = TOT * KDIM / 4;
    cast_bf16<<<(nW4 + 255) / 256, 256, 0, stream>>>(W, W_bf, nW4);

    for (int samp0 = 0; samp0 < NSAMP; samp0 += chunk) {
        dim3 grid(NUMN, chunk / 128);   // 387 x (chunk/128)
        hyper_gemm<<<grid, 256, 0, stream>>>(A_bf + (size_t)samp0 * KDIM, W_bf, b, temp);
        mlp_kernel<<<chunk, 256, 0, stream>>>(x, temp, out, samp0);
    }
}

// Round 6
// 603.461 us; speedup vs baseline: 1.2454x; 1.2454x over previous
//
#include <hip/hip_runtime.h>
#include <cstdint>
#include <cstddef>

#define NSAMP 4096
#define KDIM  512
#define TOT   49536   // 3 * (128*128 + 128)
#define TOT_P 49664   // padded to 256-multiple: 194 n-tiles
#define NUMN_P 194
#define BK    64
#define LCHUNK 16512  // 128 + 128*128, per-layer temp stride

typedef __attribute__((ext_vector_type(8))) __bf16 bf16x8;
typedef __attribute__((ext_vector_type(4))) __bf16 bf16x4;
typedef __attribute__((ext_vector_type(4))) float  f32x4;

#define AS1 __attribute__((address_space(1)))
#define AS3 __attribute__((address_space(3)))

// ---------------------------------------------------------------------------
// fp32 -> bf16 cast, 4 elements per thread (float4 read, 8B write)
// ---------------------------------------------------------------------------
__global__ void cast_bf16(const float* __restrict__ in, __bf16* __restrict__ out, int n4) {
    int i = blockIdx.x * blockDim.x + threadIdx.x;
    int stride = gridDim.x * blockDim.x;
    for (; i < n4; i += stride) {
        float4 v = ((const float4*)in)[i];
        bf16x4 o = { (__bf16)v.x, (__bf16)v.y, (__bf16)v.z, (__bf16)v.w };
        ((bf16x4*)out)[i] = o;
    }
}

// ---------------------------------------------------------------------------
// Hypernetwork GEMM: C[m][n] = sum_k A[m][k]*B[n][k] + bias[n]
// R11: 256x256 tile, 2-phase dbuf (R4's proven skeleton), BK=64, 8 waves.
// WHY: R1 vs R4 (same staged bytes, same time) + arithmetic showed the 128^2
// kernel is STAGING-BW-bound: 6192 blocks x 512KB panels = 3.17GB through L2
// per dispatch (18.6 TB/s, ~54% of L2 peak; ~2340cyc/kt/CU of L2 vs ~620cyc
// MFMA). 256^2 stages 64KB/kt for 4x the output: L2 traffic drops 4x to
// 0.79GB/dispatch. LDS 128KB -> 1 block/CU but 8 waves = 2 waves/SIMD
// (R10's fatal 1 wave/SIMD avoided). Same single-syncthreads-per-kt 2ph
// loop, same xor-granule swizzle (0 conflicts in R2's identical 256^2
// staging geometry), same XCD-congruent block swizzle.
// ---------------------------------------------------------------------------
__global__ __launch_bounds__(512, 2) void hyper_gemm(
    const __bf16* __restrict__ A, const __bf16* __restrict__ B,
    const float* __restrict__ bias, __bf16* __restrict__ C)
{
    __shared__ __bf16 As[2][256 * BK];   // 2 x 32 KB
    __shared__ __bf16 Bs[2][256 * BK];   // 2 x 32 KB

    const int tid   = threadIdx.x;
    const int lane  = tid & 63;
    const int quad  = lane >> 4;      // 0..3
    const int r16   = lane & 15;      // 0..15
    const int wv    = tid >> 6;       // 0..7
    const int waveM = wv >> 2;        // 0..1 -> 128 rows each
    const int waveN = wv & 3;         // 0..3 -> 64 cols each

    // ---- XCD-congruent swizzle: same-n_t blocks -> same XCD, adjacent ids
    const int num_m = gridDim.y;                    // chunk/256
    const int id    = blockIdx.y * NUMN_P + blockIdx.x;
    const int gsz   = 8 * num_m;                    // supergroup block count
    const int s     = id / gsz;
    const int r     = id % gsz;
    const int base  = s * 8;
    int w = NUMN_P - base; if (w > 8) w = 8;        // tail group (194%8=2)
    const int n_t = base + r % w;
    const int m_t = r / w;

    const int m0 = m_t * 256;   // chunk-local row
    const int n0 = n_t * 256;

    f32x4 acc[8][4] = {};

    // ---- per-thread staging geometry (k-invariant, hoisted)
    // idx = c*512+tid (0..2047); row = idx>>3 (0..255); granule = idx&7;
    // global granule xor-swizzled by row&7, LDS stays linear.
    const __bf16* gAp[4];
    const __bf16* gBp[4];
    int ldsOff[4];
#pragma unroll
    for (int c = 0; c < 4; ++c) {
        int idx  = c * 512 + tid;
        int row  = idx >> 3;
        int gsrc = (idx & 7) ^ (row & 7);
        gAp[c] = A + (size_t)(m0 + row) * KDIM + gsrc * 8;
        gBp[c] = B + (size_t)(n0 + row) * KDIM + gsrc * 8;
        ldsOff[c] = idx * 8;
    }

#define STAGE(buf, k0) do { \
    _Pragma("unroll") \
    for (int c = 0; c < 4; ++c) { \
        __builtin_amdgcn_global_load_lds((AS1 void*)(gAp[c] + (k0)), \
            (AS3 void*)(&As[buf][0] + ldsOff[c]), 16, 0, 0); \
        __builtin_amdgcn_global_load_lds((AS1 void*)(gBp[c] + (k0)), \
            (AS3 void*)(&Bs[buf][0] + ldsOff[c]), 16, 0, 0); \
    } \
} while (0)

    const int rsw = r16 & 7;          // read-phase swizzle key

    // ---- prologue: stage tile 0, land it
    STAGE(0, 0);
    __syncthreads();

    for (int kt = 0; kt < KDIM / BK; ++kt) {
        const int cur = kt & 1;
        // prefetch next tile into the other buffer BEFORE computing this one
        if (kt < KDIM / BK - 1) {
            STAGE(cur ^ 1, (kt + 1) * BK);
        }
        const __bf16* Ab = &As[cur][0];
        const __bf16* Bb = &Bs[cur][0];

        // --- two sub-k MFMA passes (kk = 0,1), 32 MFMA each
#pragma unroll
        for (int kk = 0; kk < 2; ++kk) {
            bf16x8 af[8], bf[4];
#pragma unroll
            for (int i = 0; i < 8; ++i) {
                int rr = waveM * 128 + i * 16 + r16;
                af[i] = *(const bf16x8*)(Ab + rr * BK + (((kk * 4 + quad) ^ rsw) * 8));
            }
#pragma unroll
            for (int j = 0; j < 4; ++j) {
                int rr = waveN * 64 + j * 16 + r16;
                bf[j] = *(const bf16x8*)(Bb + rr * BK + (((kk * 4 + quad) ^ rsw) * 8));
            }
#pragma unroll
            for (int i = 0; i < 8; ++i)
#pragma unroll
                for (int j = 0; j < 4; ++j)
                    acc[i][j] = __builtin_amdgcn_mfma_f32_16x16x32_bf16(af[i], bf[j], acc[i][j], 0, 0, 0);
        }
        // single barrier per K-iter: implicit vmcnt(0) waits for the NEXT
        // tile's loads (issued before compute), lgkmcnt(0) closes this
        // tile's ds_reads, s_barrier hands buffers off race-free.
        __syncthreads();
    }

    // --- epilogue: C/D layout col=lane&15, row=(lane>>4)*4+reg. Fuse bias,
    // cast bf16, plain stores. Pad columns (n >= TOT) get zero-bias garbage;
    // the MLP stage never reads them (row stride TOT_P).
#pragma unroll
    for (int j = 0; j < 4; ++j) {
        int n = n0 + waveN * 64 + j * 16 + r16;
        float bb = (n < TOT) ? bias[n] : 0.f;
#pragma unroll
        for (int i = 0; i < 8; ++i) {
            int mbase = m0 + waveM * 128 + i * 16 + quad * 4;
#pragma unroll
            for (int rr = 0; rr < 4; ++rr) {
                C[(size_t)(mbase + rr) * TOT_P + n] = (__bf16)(acc[i][j][rr] + bb);
            }
        }
    }
#undef STAGE
}

// ---------------------------------------------------------------------------
// Stage 2: per-sample 3-layer MLP with hypernetwork weights from temp chunk.
// Unchanged logic (T14 cross-layer weight prefetch; bias hoisted); temp row
// stride = TOT_P.
// ---------------------------------------------------------------------------
__global__ __launch_bounds__(256) void mlp_kernel(
    const float* __restrict__ x, const __bf16* __restrict__ temp,
    float* __restrict__ out, int samp0)
{
    const int n   = samp0 + blockIdx.x;   // global sample index
    const int tid = threadIdx.x;
    const int wv  = tid >> 6;             // 0..3
    const int l   = tid & 63;
    const int pg  = l >> 4;               // 0..3
    const int qg  = l & 15;               // 0..15

    __shared__ float h[128];
    __shared__ float partial[4][128];

    if (tid < 64) ((float2*)h)[tid] = ((const float2*)(x + (size_t)n * 128))[tid];

    const __bf16* row = temp + (size_t)blockIdx.x * TOT_P;  // padded row stride

    // prefetch layer-0 weights (independent of h)
    bf16x8 w[8];
#pragma unroll
    for (int i = 0; i < 8; ++i)
        w[i] = *(const bf16x8*)(row + 128 + (size_t)(wv * 32 + i * 4 + pg) * 128 + qg * 8);

    int cum = 0;
#pragma unroll
    for (int layer = 0; layer < 3; ++layer) {
        bf16x8 wn[8];
        if (layer < 2) {
#pragma unroll
            for (int i = 0; i < 8; ++i)
                wn[i] = *(const bf16x8*)(row + cum + LCHUNK + 128
                        + (size_t)(wv * 32 + i * 4 + pg) * 128 + qg * 8);
        }
        float bv = 0.f;
        if (tid < 128) bv = (float)row[cum + tid];

        float acc[8] = {0, 0, 0, 0, 0, 0, 0, 0};
        __syncthreads();   // h ready
#pragma unroll
        for (int i = 0; i < 8; ++i) {
            float hp = h[wv * 32 + i * 4 + pg];
#pragma unroll
            for (int j = 0; j < 8; ++j) acc[j] += (float)w[i][j] * hp;
        }
#pragma unroll
        for (int j = 0; j < 8; ++j) {
            acc[j] += __shfl_xor(acc[j], 16);
            acc[j] += __shfl_xor(acc[j], 32);
        }
        if (pg == 0) {
#pragma unroll
            for (int j = 0; j < 8; ++j) partial[wv][qg * 8 + j] = acc[j];
        }
        __syncthreads();   // partials ready; everyone done reading h
        if (tid < 128) {
            float v = partial[0][tid] + partial[1][tid] + partial[2][tid] + partial[3][tid]
                    + bv;
            if (layer < 2) v = fmaxf(v, 0.f);
            h[tid] = v;
        }
        if (layer < 2) {
#pragma unroll
            for (int i = 0; i < 8; ++i) w[i] = wn[i];
        }
        cum += LCHUNK;
    }
    __syncthreads();
    if (tid < 64) ((float2*)(out + (size_t)n * 128))[tid] = ((const float2*)h)[tid];
}

// ---------------------------------------------------------------------------
extern "C" void kernel_launch(void* const* d_in, const int* in_sizes, int n_in,
                              void* d_out, int out_size, void* d_ws, size_t ws_size,
                              hipStream_t stream) {
    const float* int_x = (const float*)d_in[0];  // 4096 x 512
    const float* x     = (const float*)d_in[1];  // 4096 x 128
    const float* W     = (const float*)d_in[2];  // 49536 x 512
    const float* b     = (const float*)d_in[3];  // 49536
    float* out = (float*)d_out;                  // 4096 x 128

    // workspace layout (bf16): A_bf (4 MB) | W_bf (TOT_P rows) | temp chunk
    char* ws = (char*)d_ws;
    __bf16* A_bf = (__bf16*)ws;
    size_t offA = (size_t)NSAMP * KDIM * 2;
    __bf16* W_bf = (__bf16*)(ws + offA);
    size_t offW = offA + (size_t)TOT_P * KDIM * 2;
    __bf16* temp = (__bf16*)(ws + offW);

    // Adaptive chunk: largest of {4096..256} whose padded temp fits remaining
    // ws. Deterministic given ws_size (capture-safe). chunk % 256 == 0.
    size_t remain = (ws_size > offW) ? (ws_size - offW) : 0;
    int chunk = 256;
    for (int c = 4096; c >= 256; c >>= 1) {
        if ((size_t)c * TOT_P * 2 <= remain) { chunk = c; break; }
    }

    int nA4 = NSAMP * KDIM / 4;
    cast_bf16<<<(nA4 + 255) / 256, 256, 0, stream>>>(int_x, A_bf, nA4);
    int nW4 = TOT * KDIM / 4;
    cast_bf16<<<(nW4 + 255) / 256, 256, 0, stream>>>(W, W_bf, nW4);
    // zero the 128 pad rows of W_bf (avoid stale-garbage NaN/Inf surprises)
    hipMemsetAsync(W_bf + (size_t)TOT * KDIM, 0, (size_t)(TOT_P - TOT) * KDIM * 2, stream);

    for (int samp0 = 0; samp0 < NSAMP; samp0 += chunk) {
        dim3 grid(NUMN_P, chunk / 256);   // 194 x (chunk/256)
        hyper_gemm<<<grid, 512, 0, stream>>>(A_bf + (size_t)samp0 * KDIM, W_bf, b, temp);
        mlp_kernel<<<chunk, 256, 0, stream>>>(x, temp, out, samp0);
    }
}